// Round 16
// baseline (213.477 us; speedup 1.0000x reference)
//
#include <hip/hip_runtime.h>

#define FD 96
#define BSH 7       // 128 nodes per bucket
#define BNODES 128
#define NBLK 256    // blocks for 2D-histogram scatter

typedef float  f32x4 __attribute__((ext_vector_type(4)));
typedef short  s16x8 __attribute__((ext_vector_type(8)));

__device__ __forceinline__ unsigned short f2bf(float x) {
    unsigned u = __float_as_uint(x);
    u = (u + 0x7fffu + ((u >> 16) & 1u)) >> 16;
    return (unsigned short)u;
}
__device__ __forceinline__ float bflo(unsigned u) { return __uint_as_float(u << 16); }
__device__ __forceinline__ float bfhi(unsigned u) { return __uint_as_float(u & 0xffff0000u); }

// ---------------- bucketed CSR build (contention-free, 6 kernels) ----------------

__global__ void k_h2d(const int* __restrict__ dst, int* __restrict__ hist2d,
                      int E, int nbkt, int chunk) {
    __shared__ int hist[512];
    int tid = threadIdx.x, b = blockIdx.x;
    for (int i = tid; i < 512; i += 256) hist[i] = 0;
    __syncthreads();
    int lo = b * chunk, hi = min(lo + chunk, E);
    for (int i = lo + tid; i < hi; i += 256)
        atomicAdd(&hist[dst[i] >> BSH], 1);
    __syncthreads();
    for (int q = tid; q < nbkt; q += 256)
        hist2d[(size_t)q * NBLK + b] = hist[q];
}

// per-bucket column scan; block 0 zeroes both BN acc arrays (4*FD floats)
__global__ void k_cscan(const int* __restrict__ hist2d, int* __restrict__ cursor2d,
                        int* __restrict__ bcnt, float* __restrict__ accz) {
    __shared__ int sh[NBLK];
    int q = blockIdx.x, tid = threadIdx.x;
    if (q == 0) for (int i = tid; i < 4 * FD; i += 256) accz[i] = 0.f;
    int v = hist2d[(size_t)q * NBLK + tid];
    sh[tid] = v;
    __syncthreads();
    for (int off = 1; off < NBLK; off <<= 1) {
        int t = (tid >= off) ? sh[tid - off] : 0;
        __syncthreads();
        sh[tid] += t;
        __syncthreads();
    }
    cursor2d[(size_t)q * NBLK + tid] = sh[tid] - v;
    if (tid == NBLK - 1) bcnt[q] = sh[tid];
}

__global__ void k_bscan(const int* __restrict__ bcnt, int* __restrict__ bbase, int nbkt) {
    __shared__ int sh[512];
    int tid = threadIdx.x;
    int v = (tid < nbkt) ? bcnt[tid] : 0;
    sh[tid] = v;
    __syncthreads();
    for (int off = 1; off < 512; off <<= 1) {
        int t = (tid >= off) ? sh[tid - off] : 0;
        __syncthreads();
        sh[tid] += t;
        __syncthreads();
    }
    int incl = sh[tid];
    if (tid < nbkt) bbase[tid] = incl - v;
    if (tid == nbkt - 1) bbase[nbkt] = incl;
}

__global__ void k_scat(const int* __restrict__ src, const int* __restrict__ dst,
                       const int* __restrict__ cursor2d, const int* __restrict__ bbase,
                       uint2* __restrict__ ebuf, int E, int nbkt, int chunk) {
    __shared__ int cur[512];
    int tid = threadIdx.x, b = blockIdx.x;
    for (int q = tid; q < nbkt; q += 256)
        cur[q] = bbase[q] + cursor2d[(size_t)q * NBLK + b];
    __syncthreads();
    int lo = b * chunk, hi = min(lo + chunk, E);
    for (int i = lo + tid; i < hi; i += 256) {
        int d = dst[i];
        int p = atomicAdd(&cur[d >> BSH], 1);
        ebuf[p] = make_uint2((unsigned)d, (unsigned)src[i]);
    }
}

// per-bucket counting sort. perm rank is DESCENDING degree (LPT): longest rows get the
// lowest slots -> longest agg blocks are scheduled first, shrinking the makespan tail.
__global__ void k_bsort(const uint2* __restrict__ ebuf, const int* __restrict__ bbase,
                        int* __restrict__ csr, int* __restrict__ rp2, int* __restrict__ re2,
                        float* __restrict__ invd2, int* __restrict__ perm,
                        int* __restrict__ inv_perm, int n) {
    __shared__ int cnt[BNODES];
    __shared__ int cur[BNODES];
    __shared__ int dh[64];
    const int b = blockIdx.x;
    const int tid = threadIdx.x;
    const int lo = bbase[b], hi = bbase[b + 1];
    if (tid < BNODES) cnt[tid] = 0;
    if (tid < 64) dh[tid] = 0;
    __syncthreads();
    for (int i = lo + tid; i < hi; i += blockDim.x)
        atomicAdd(&cnt[(int)ebuf[i].x - (b << BSH)], 1);
    __syncthreads();
    const int node = (b << BSH) + tid;
    const int v = (tid < BNODES) ? cnt[tid] : 0;
    const int dcl = 63 - min(v, 63);   // descending-degree class (LPT)
    if (tid < BNODES && node < n) atomicAdd(&dh[dcl], 1);
    for (int off = 1; off < BNODES; off <<= 1) {
        int t = (tid < BNODES && tid >= off) ? cnt[tid - off] : 0;
        __syncthreads();
        if (tid < BNODES) cnt[tid] += t;
        __syncthreads();
    }
    int dv = (tid < 64) ? dh[tid] : 0;
    for (int off = 1; off < 64; off <<= 1) {
        int t = (tid < 64 && tid >= off) ? dh[tid - off] : 0;
        __syncthreads();
        if (tid < 64) dh[tid] += t;
        __syncthreads();
    }
    if (tid < 64) dh[tid] -= dv;
    __syncthreads();
    if (tid < BNODES) {
        int excl = cnt[tid] - v;
        if (node < n) {
            int rk = atomicAdd(&dh[dcl], 1);
            int slot = (b << BSH) + rk;
            perm[slot] = node;
            inv_perm[node] = slot;
            rp2[slot] = lo + excl;
            re2[slot] = lo + excl + v;
            invd2[slot] = (v > 0) ? (1.0f / (float)v) : 0.f;
        }
        cur[tid] = excl;
    }
    __syncthreads();
    for (int i = lo + tid; i < hi; i += blockDim.x) {
        uint2 e2 = ebuf[i];
        int local = (int)e2.x - (b << BSH);
        int p = lo + atomicAdd(&cur[local], 1);
        csr[p] = (int)e2.y;
    }
}

// fused prep: csr translate + feature cvt to perm order + W transpose/cvt
__global__ void k_prep(int* __restrict__ csr, const int* __restrict__ inv_perm, int E,
                       const float* __restrict__ feat, const int* __restrict__ perm,
                       uint4* __restrict__ hA, int n,
                       const float* __restrict__ W1, const float* __restrict__ W2,
                       const float* __restrict__ W3, unsigned short* __restrict__ Wt) {
    int i = blockIdx.x * blockDim.x + threadIdx.x;
    if (i < E) {
        csr[i] = inv_perm[csr[i]];
        return;
    }
    i -= E;
    const int n12 = n * 12;
    if (i < n12) {
        int row = i / 12, q = i - row * 12;
        int node = perm[row];
        const float4* rp = (const float4*)(feat + (size_t)node * FD);
        float4 x = rp[2 * q], y = rp[2 * q + 1];
        uint4 r;
        r.x = (unsigned)f2bf(x.x) | ((unsigned)f2bf(x.y) << 16);
        r.y = (unsigned)f2bf(x.z) | ((unsigned)f2bf(x.w) << 16);
        r.z = (unsigned)f2bf(y.x) | ((unsigned)f2bf(y.y) << 16);
        r.w = (unsigned)f2bf(y.z) | ((unsigned)f2bf(y.w) << 16);
        hA[i] = r;
        return;
    }
    i -= n12;
    if (i < 3 * FD * FD) {
        int m = i / (FD * FD), r = i - m * FD * FD;
        const float* W = (m == 0) ? W1 : ((m == 1) ? W2 : W3);
        int col = r % FD, k = r / FD;
        Wt[m * FD * FD + col * FD + k] = f2bf(W[r]);
    }
}

// ---------------- aggregation: 12 threads/row (max TLP), BN of prev layer folded ----------------

template<int NORM>
__global__ __launch_bounds__(256, 4) void k_agg(
    const uint4* __restrict__ h,
    const int* __restrict__ rp2, const int* __restrict__ re2,
    const float* __restrict__ invd2, const int* __restrict__ csr,
    const float* __restrict__ accPrev, const float* __restrict__ gamma,
    const float* __restrict__ beta, float invN,
    uint4* __restrict__ t, int n)
{
    int g = blockIdx.x * blockDim.x + threadIdx.x;
    int row = g / 12;
    if (row >= n) return;
    int q = g - row * 12;
    float a[8], c[8];
    if (NORM) {
        #pragma unroll
        for (int z = 0; z < 8; z++) {
            int f = q * 8 + z;
            float mu  = accPrev[f] * invN;
            float var = accPrev[FD + f] * invN - mu * mu;
            float aa  = gamma[f] * rsqrtf(var + 1e-5f);
            a[z] = aa;
            c[z] = beta[f] - mu * aa;
        }
    }
    float acc8[8];
    #pragma unroll
    for (int z = 0; z < 8; z++) acc8[z] = 0.f;

    int e = rp2[row];
    const int end = re2[row];
    for (; e + 8 <= end; e += 8) {
        uint4 raw[8];
        #pragma unroll
        for (int u = 0; u < 8; u++) raw[u] = h[(size_t)csr[e + u] * 12 + q];
        #pragma unroll
        for (int u = 0; u < 8; u++) {
            float v[8];
            v[0] = bflo(raw[u].x); v[1] = bfhi(raw[u].x);
            v[2] = bflo(raw[u].y); v[3] = bfhi(raw[u].y);
            v[4] = bflo(raw[u].z); v[5] = bfhi(raw[u].z);
            v[6] = bflo(raw[u].w); v[7] = bfhi(raw[u].w);
            #pragma unroll
            for (int z = 0; z < 8; z++) {
                float x = v[z];
                if (NORM) x = fmaxf(fmaf(a[z], x, c[z]), 0.f);
                acc8[z] += x;
            }
        }
    }
    for (; e < end; e++) {
        uint4 raw = h[(size_t)csr[e] * 12 + q];
        float v[8];
        v[0] = bflo(raw.x); v[1] = bfhi(raw.x);
        v[2] = bflo(raw.y); v[3] = bfhi(raw.y);
        v[4] = bflo(raw.z); v[5] = bfhi(raw.z);
        v[6] = bflo(raw.w); v[7] = bfhi(raw.w);
        #pragma unroll
        for (int z = 0; z < 8; z++) {
            float x = v[z];
            if (NORM) x = fmaxf(fmaf(a[z], x, c[z]), 0.f);
            acc8[z] += x;
        }
    }
    uint4 rs = h[(size_t)row * 12 + q];
    float xs[8];
    xs[0] = bflo(rs.x); xs[1] = bfhi(rs.x);
    xs[2] = bflo(rs.y); xs[3] = bfhi(rs.y);
    xs[4] = bflo(rs.z); xs[5] = bfhi(rs.z);
    xs[6] = bflo(rs.w); xs[7] = bfhi(rs.w);
    float id = invd2[row];
    float o[8];
    #pragma unroll
    for (int z = 0; z < 8; z++) {
        float x = xs[z];
        if (NORM) x = fmaxf(fmaf(a[z], x, c[z]), 0.f);
        o[z] = fmaf(id, acc8[z], x);
    }
    uint4 pk;
    pk.x = (unsigned)f2bf(o[0]) | ((unsigned)f2bf(o[1]) << 16);
    pk.y = (unsigned)f2bf(o[2]) | ((unsigned)f2bf(o[3]) << 16);
    pk.z = (unsigned)f2bf(o[4]) | ((unsigned)f2bf(o[5]) << 16);
    pk.w = (unsigned)f2bf(o[6]) | ((unsigned)f2bf(o[7]) << 16);
    t[(size_t)row * 12 + q] = pk;
}

// ---------------- MFMA matmul: y = t @ W + b (rows are perm slots) ----------------

template<int STATS, int OBF>
__global__ void k_mm(const unsigned short* __restrict__ ta,
                     const unsigned short* __restrict__ Wt,
                     const float* __restrict__ bias, const int* __restrict__ perm,
                     unsigned short* __restrict__ yb, float* __restrict__ yf,
                     float* __restrict__ accg, int n)
{
    __shared__ float sred[2 * FD];
    const int tid  = threadIdx.x;
    const int lane = tid & 63;
    const int wv   = tid >> 6;
    const int colb = lane & 15;
    const int hg   = lane >> 4;
    const int rbase = blockIdx.x * 64 + wv * 16;
    const int r = rbase + colb;

    s16x8 a[3];
    if (r < n) {
        #pragma unroll
        for (int s = 0; s < 3; s++)
            a[s] = *reinterpret_cast<const s16x8*>(ta + (size_t)r * FD + s * 32 + hg * 8);
    } else {
        #pragma unroll
        for (int s = 0; s < 3; s++) a[s] = s16x8{0, 0, 0, 0, 0, 0, 0, 0};
    }
    s16x8 b[6][3];
    #pragma unroll
    for (int c2 = 0; c2 < 6; c2++)
        #pragma unroll
        for (int s = 0; s < 3; s++)
            b[c2][s] = *reinterpret_cast<const s16x8*>(Wt + (size_t)(c2 * 16 + colb) * FD + s * 32 + hg * 8);

    f32x4 acc[6];
    #pragma unroll
    for (int c2 = 0; c2 < 6; c2++) acc[c2] = (f32x4){0.f, 0.f, 0.f, 0.f};
    #pragma unroll
    for (int s = 0; s < 3; s++)
        #pragma unroll
        for (int c2 = 0; c2 < 6; c2++)
            acc[c2] = __builtin_amdgcn_mfma_f32_16x16x32_bf16(a[s], b[c2][s], acc[c2], 0, 0, 0);

    int orow[4];
    #pragma unroll
    for (int j = 0; j < 4; j++) {
        int rr = rbase + hg * 4 + j;
        orow[j] = (!OBF && rr < n) ? perm[rr] : rr;
    }
    float s1[6], s2[6];
    #pragma unroll
    for (int c2 = 0; c2 < 6; c2++) { s1[c2] = 0.f; s2[c2] = 0.f; }
    #pragma unroll
    for (int c2 = 0; c2 < 6; c2++) {
        float bc = bias[c2 * 16 + colb];
        #pragma unroll
        for (int j = 0; j < 4; j++) {
            int rr = rbase + hg * 4 + j;
            if (rr < n) {
                float y = acc[c2][j] + bc;
                if (OBF) yb[(size_t)rr * FD + c2 * 16 + colb] = f2bf(y);
                else     yf[(size_t)orow[j] * FD + c2 * 16 + colb] = y;
                if (STATS) { s1[c2] += y; s2[c2] = fmaf(y, y, s2[c2]); }
            }
        }
    }
    if (STATS) {
        if (tid < 2 * FD) sred[tid] = 0.f;
        __syncthreads();
        #pragma unroll
        for (int c2 = 0; c2 < 6; c2++) {
            float v1 = s1[c2], v2 = s2[c2];
            v1 += __shfl_xor(v1, 16, 64); v1 += __shfl_xor(v1, 32, 64);
            v2 += __shfl_xor(v2, 16, 64); v2 += __shfl_xor(v2, 32, 64);
            if (lane < 16) {
                atomicAdd(&sred[c2 * 16 + colb], v1);
                atomicAdd(&sred[FD + c2 * 16 + colb], v2);
            }
        }
        __syncthreads();
        if (tid < 2 * FD) atomicAdd(&accg[tid], sred[tid]);
    }
}

extern "C" void kernel_launch(void* const* d_in, const int* in_sizes, int n_in,
                              void* d_out, int out_size, void* d_ws, size_t ws_size,
                              hipStream_t stream) {
    const float* feat = (const float*)d_in[0];
    const float* W1   = (const float*)d_in[1];
    const float* b1   = (const float*)d_in[2];
    const float* g1   = (const float*)d_in[3];
    const float* be1  = (const float*)d_in[4];
    const float* W2   = (const float*)d_in[5];
    const float* b2   = (const float*)d_in[6];
    const float* g2   = (const float*)d_in[7];
    const float* be2  = (const float*)d_in[8];
    const float* W3   = (const float*)d_in[9];
    const float* b3   = (const float*)d_in[10];
    const int*   src  = (const int*)d_in[11];
    const int*   dst  = (const int*)d_in[12];

    const int n = in_sizes[0] / FD;   // 50000
    const int e = in_sizes[11];       // 800000
    const int nbkt = (n + BNODES - 1) >> BSH;     // 391
    const int chunk = (e + NBLK - 1) / NBLK;      // 3125

    char* w = (char*)d_ws;
    unsigned short* hA  = (unsigned short*)w; w += (size_t)n * FD * 2;   // perm-order h
    unsigned short* tb  = (unsigned short*)w; w += (size_t)n * FD * 2;   // t buffer (ebuf alias)
    unsigned short* Wt  = (unsigned short*)w; w += (size_t)3 * FD * FD * 2;
    int*   csr     = (int*)w;   w += (size_t)e * 4;
    int*   bcnt    = (int*)w;   w += 512 * 4;
    float* acc1    = (float*)w; w += 2 * FD * 4;   // zeroed by k_cscan (with acc2)
    float* acc2    = (float*)w; w += 2 * FD * 4;
    int*   bbase   = (int*)w;   w += 513 * 4;
    int*   hist2d  = (int*)w;   w += (size_t)512 * NBLK * 4;
    int*   cursor2d= (int*)w;   w += (size_t)512 * NBLK * 4;
    int*   rp2     = (int*)w;   w += (size_t)n * 4;
    int*   re2     = (int*)w;   w += (size_t)n * 4;
    float* invd2   = (float*)w; w += (size_t)n * 4;
    int*   perm    = (int*)w;   w += (size_t)n * 4;
    int*   invp    = (int*)w;   w += (size_t)n * 4;

    uint2* ebuf = (uint2*)tb;                      // dead after k_bsort
    unsigned short* hB = (unsigned short*)d_out;   // bf16 ping-pong inside d_out
    float* O = (float*)d_out;
    const float invN = 1.0f / (float)n;
    const int AGG_GRID = (n * 12 + 255) / 256;     // 2344
    const int MM_GRID  = (n + 63) / 64;            // 782
    const int n12 = n * 12;
    const int prep_items = e + n12 + 3 * FD * FD;

    k_h2d<<<NBLK, 256, 0, stream>>>(dst, hist2d, e, nbkt, chunk);
    k_cscan<<<nbkt, NBLK, 0, stream>>>(hist2d, cursor2d, bcnt, acc1);
    k_bscan<<<1, 512, 0, stream>>>(bcnt, bbase, nbkt);
    k_scat<<<NBLK, 256, 0, stream>>>(src, dst, cursor2d, bbase, ebuf, e, nbkt, chunk);
    k_bsort<<<nbkt, 256, 0, stream>>>(ebuf, bbase, csr, rp2, re2, invd2, perm, invp, n);
    k_prep<<<(prep_items + 255) / 256, 256, 0, stream>>>(csr, invp, e, feat, perm,
                                                         (uint4*)hA, n, W1, W2, W3, Wt);

    // layer 1: agg hA->tb, mm tb->hB (bf16 in d_out), stats->acc1
    k_agg<0><<<AGG_GRID, 256, 0, stream>>>((const uint4*)hA, rp2, re2, invd2, csr,
                                           nullptr, nullptr, nullptr, invN, (uint4*)tb, n);
    k_mm<1, 1><<<MM_GRID, 256, 0, stream>>>(tb, Wt, b1, perm, hB, nullptr, acc1, n);

    // layer 2: agg hB->tb (BN from acc1), mm tb->hA, stats->acc2
    k_agg<1><<<AGG_GRID, 256, 0, stream>>>((const uint4*)hB, rp2, re2, invd2, csr,
                                           acc1, g1, be1, invN, (uint4*)tb, n);
    k_mm<1, 1><<<MM_GRID, 256, 0, stream>>>(tb, Wt + FD * FD, b2, perm, hA, nullptr, acc2, n);

    // layer 3: agg hA->tb (BN from acc2), mm tb->d_out fp32 (original order via perm)
    k_agg<1><<<AGG_GRID, 256, 0, stream>>>((const uint4*)hA, rp2, re2, invd2, csr,
                                           acc2, g2, be2, invN, (uint4*)tb, n);
    k_mm<0, 0><<<MM_GRID, 256, 0, stream>>>(tb, Wt + 2 * FD * FD, b3, perm, nullptr, O, nullptr, n);
}

// Round 17
// 210.132 us; speedup vs baseline: 1.0159x; 1.0159x over previous
//
#include <hip/hip_runtime.h>

#define FD 96
#define BSH 7       // 128 nodes per bucket
#define BNODES 128
#define NBLK 256    // blocks for 2D-histogram scatter

typedef float  f32x4 __attribute__((ext_vector_type(4)));
typedef short  s16x8 __attribute__((ext_vector_type(8)));

__device__ __forceinline__ unsigned short f2bf(float x) {
    unsigned u = __float_as_uint(x);
    u = (u + 0x7fffu + ((u >> 16) & 1u)) >> 16;
    return (unsigned short)u;
}
__device__ __forceinline__ float bflo(unsigned u) { return __uint_as_float(u << 16); }
__device__ __forceinline__ float bfhi(unsigned u) { return __uint_as_float(u & 0xffff0000u); }

// ---------------- bucketed CSR build (contention-free, 6 kernels) ----------------

__global__ void k_h2d(const int* __restrict__ dst, int* __restrict__ hist2d,
                      int E, int nbkt, int chunk) {
    __shared__ int hist[512];
    int tid = threadIdx.x, b = blockIdx.x;
    for (int i = tid; i < 512; i += 256) hist[i] = 0;
    __syncthreads();
    int lo = b * chunk, hi = min(lo + chunk, E);
    for (int i = lo + tid; i < hi; i += 256)
        atomicAdd(&hist[dst[i] >> BSH], 1);
    __syncthreads();
    for (int q = tid; q < nbkt; q += 256)
        hist2d[(size_t)q * NBLK + b] = hist[q];
}

// per-bucket column scan; block 0 zeroes both BN acc arrays (4*FD floats)
__global__ void k_cscan(const int* __restrict__ hist2d, int* __restrict__ cursor2d,
                        int* __restrict__ bcnt, float* __restrict__ accz) {
    __shared__ int sh[NBLK];
    int q = blockIdx.x, tid = threadIdx.x;
    if (q == 0) for (int i = tid; i < 4 * FD; i += 256) accz[i] = 0.f;
    int v = hist2d[(size_t)q * NBLK + tid];
    sh[tid] = v;
    __syncthreads();
    for (int off = 1; off < NBLK; off <<= 1) {
        int t = (tid >= off) ? sh[tid - off] : 0;
        __syncthreads();
        sh[tid] += t;
        __syncthreads();
    }
    cursor2d[(size_t)q * NBLK + tid] = sh[tid] - v;
    if (tid == NBLK - 1) bcnt[q] = sh[tid];
}

__global__ void k_bscan(const int* __restrict__ bcnt, int* __restrict__ bbase, int nbkt) {
    __shared__ int sh[512];
    int tid = threadIdx.x;
    int v = (tid < nbkt) ? bcnt[tid] : 0;
    sh[tid] = v;
    __syncthreads();
    for (int off = 1; off < 512; off <<= 1) {
        int t = (tid >= off) ? sh[tid - off] : 0;
        __syncthreads();
        sh[tid] += t;
        __syncthreads();
    }
    int incl = sh[tid];
    if (tid < nbkt) bbase[tid] = incl - v;
    if (tid == nbkt - 1) bbase[nbkt] = incl;
}

__global__ void k_scat(const int* __restrict__ src, const int* __restrict__ dst,
                       const int* __restrict__ cursor2d, const int* __restrict__ bbase,
                       uint2* __restrict__ ebuf, int E, int nbkt, int chunk) {
    __shared__ int cur[512];
    int tid = threadIdx.x, b = blockIdx.x;
    for (int q = tid; q < nbkt; q += 256)
        cur[q] = bbase[q] + cursor2d[(size_t)q * NBLK + b];
    __syncthreads();
    int lo = b * chunk, hi = min(lo + chunk, E);
    for (int i = lo + tid; i < hi; i += 256) {
        int d = dst[i];
        int p = atomicAdd(&cur[d >> BSH], 1);
        ebuf[p] = make_uint2((unsigned)d, (unsigned)src[i]);
    }
}

// per-bucket counting sort -> csr (orig src ids), perm-ordered rp2/re2/invd2, perm, inv_perm
// perm rank: ascending degree within bucket (R15 proven best).
__global__ void k_bsort(const uint2* __restrict__ ebuf, const int* __restrict__ bbase,
                        int* __restrict__ csr, int* __restrict__ rp2, int* __restrict__ re2,
                        float* __restrict__ invd2, int* __restrict__ perm,
                        int* __restrict__ inv_perm, int n) {
    __shared__ int cnt[BNODES];
    __shared__ int cur[BNODES];
    __shared__ int dh[64];
    const int b = blockIdx.x;
    const int tid = threadIdx.x;
    const int lo = bbase[b], hi = bbase[b + 1];
    if (tid < BNODES) cnt[tid] = 0;
    if (tid < 64) dh[tid] = 0;
    __syncthreads();
    for (int i = lo + tid; i < hi; i += blockDim.x)
        atomicAdd(&cnt[(int)ebuf[i].x - (b << BSH)], 1);
    __syncthreads();
    const int node = (b << BSH) + tid;
    const int v = (tid < BNODES) ? cnt[tid] : 0;
    const int dcl = min(v, 63);
    if (tid < BNODES && node < n) atomicAdd(&dh[dcl], 1);
    for (int off = 1; off < BNODES; off <<= 1) {
        int t = (tid < BNODES && tid >= off) ? cnt[tid - off] : 0;
        __syncthreads();
        if (tid < BNODES) cnt[tid] += t;
        __syncthreads();
    }
    int dv = (tid < 64) ? dh[tid] : 0;
    for (int off = 1; off < 64; off <<= 1) {
        int t = (tid < 64 && tid >= off) ? dh[tid - off] : 0;
        __syncthreads();
        if (tid < 64) dh[tid] += t;
        __syncthreads();
    }
    if (tid < 64) dh[tid] -= dv;
    __syncthreads();
    if (tid < BNODES) {
        int excl = cnt[tid] - v;
        if (node < n) {
            int rk = atomicAdd(&dh[dcl], 1);
            int slot = (b << BSH) + rk;
            perm[slot] = node;
            inv_perm[node] = slot;
            rp2[slot] = lo + excl;
            re2[slot] = lo + excl + v;
            invd2[slot] = (v > 0) ? (1.0f / (float)v) : 0.f;
        }
        cur[tid] = excl;
    }
    __syncthreads();
    for (int i = lo + tid; i < hi; i += blockDim.x) {
        uint2 e2 = ebuf[i];
        int local = (int)e2.x - (b << BSH);
        int p = lo + atomicAdd(&cur[local], 1);
        csr[p] = (int)e2.y;
    }
}

// fused prep: csr translate + feature cvt to perm order + W transpose/cvt
__global__ void k_prep(int* __restrict__ csr, const int* __restrict__ inv_perm, int E,
                       const float* __restrict__ feat, const int* __restrict__ perm,
                       uint4* __restrict__ hA, int n,
                       const float* __restrict__ W1, const float* __restrict__ W2,
                       const float* __restrict__ W3, unsigned short* __restrict__ Wt) {
    int i = blockIdx.x * blockDim.x + threadIdx.x;
    if (i < E) {
        csr[i] = inv_perm[csr[i]];
        return;
    }
    i -= E;
    const int n12 = n * 12;
    if (i < n12) {
        int row = i / 12, q = i - row * 12;
        int node = perm[row];
        const float4* rp = (const float4*)(feat + (size_t)node * FD);
        float4 x = rp[2 * q], y = rp[2 * q + 1];
        uint4 r;
        r.x = (unsigned)f2bf(x.x) | ((unsigned)f2bf(x.y) << 16);
        r.y = (unsigned)f2bf(x.z) | ((unsigned)f2bf(x.w) << 16);
        r.z = (unsigned)f2bf(y.x) | ((unsigned)f2bf(y.y) << 16);
        r.w = (unsigned)f2bf(y.z) | ((unsigned)f2bf(y.w) << 16);
        hA[i] = r;
        return;
    }
    i -= n12;
    if (i < 3 * FD * FD) {
        int m = i / (FD * FD), r = i - m * FD * FD;
        const float* W = (m == 0) ? W1 : ((m == 1) ? W2 : W3);
        int col = r % FD, k = r / FD;
        Wt[m * FD * FD + col * FD + k] = f2bf(W[r]);
    }
}

// ---------------- aggregation: 12 threads/row (max TLP), BN of prev layer folded ----------------

template<int NORM>
__global__ __launch_bounds__(256, 4) void k_agg(
    const uint4* __restrict__ h,
    const int* __restrict__ rp2, const int* __restrict__ re2,
    const float* __restrict__ invd2, const int* __restrict__ csr,
    const float* __restrict__ accPrev, const float* __restrict__ gamma,
    const float* __restrict__ beta, float invN,
    uint4* __restrict__ t, int n)
{
    int g = blockIdx.x * blockDim.x + threadIdx.x;
    int row = g / 12;
    if (row >= n) return;
    int q = g - row * 12;
    float a[8], c[8];
    if (NORM) {
        #pragma unroll
        for (int z = 0; z < 8; z++) {
            int f = q * 8 + z;
            float mu  = accPrev[f] * invN;
            float var = accPrev[FD + f] * invN - mu * mu;
            float aa  = gamma[f] * rsqrtf(var + 1e-5f);
            a[z] = aa;
            c[z] = beta[f] - mu * aa;
        }
    }
    float acc8[8];
    #pragma unroll
    for (int z = 0; z < 8; z++) acc8[z] = 0.f;

    int e = rp2[row];
    const int end = re2[row];
    for (; e + 8 <= end; e += 8) {
        uint4 raw[8];
        #pragma unroll
        for (int u = 0; u < 8; u++) raw[u] = h[(size_t)csr[e + u] * 12 + q];
        #pragma unroll
        for (int u = 0; u < 8; u++) {
            float v[8];
            v[0] = bflo(raw[u].x); v[1] = bfhi(raw[u].x);
            v[2] = bflo(raw[u].y); v[3] = bfhi(raw[u].y);
            v[4] = bflo(raw[u].z); v[5] = bfhi(raw[u].z);
            v[6] = bflo(raw[u].w); v[7] = bfhi(raw[u].w);
            #pragma unroll
            for (int z = 0; z < 8; z++) {
                float x = v[z];
                if (NORM) x = fmaxf(fmaf(a[z], x, c[z]), 0.f);
                acc8[z] += x;
            }
        }
    }
    for (; e < end; e++) {
        uint4 raw = h[(size_t)csr[e] * 12 + q];
        float v[8];
        v[0] = bflo(raw.x); v[1] = bfhi(raw.x);
        v[2] = bflo(raw.y); v[3] = bfhi(raw.y);
        v[4] = bflo(raw.z); v[5] = bfhi(raw.z);
        v[6] = bflo(raw.w); v[7] = bfhi(raw.w);
        #pragma unroll
        for (int z = 0; z < 8; z++) {
            float x = v[z];
            if (NORM) x = fmaxf(fmaf(a[z], x, c[z]), 0.f);
            acc8[z] += x;
        }
    }
    uint4 rs = h[(size_t)row * 12 + q];
    float xs[8];
    xs[0] = bflo(rs.x); xs[1] = bfhi(rs.x);
    xs[2] = bflo(rs.y); xs[3] = bfhi(rs.y);
    xs[4] = bflo(rs.z); xs[5] = bfhi(rs.z);
    xs[6] = bflo(rs.w); xs[7] = bfhi(rs.w);
    float id = invd2[row];
    float o[8];
    #pragma unroll
    for (int z = 0; z < 8; z++) {
        float x = xs[z];
        if (NORM) x = fmaxf(fmaf(a[z], x, c[z]), 0.f);
        o[z] = fmaf(id, acc8[z], x);
    }
    uint4 pk;
    pk.x = (unsigned)f2bf(o[0]) | ((unsigned)f2bf(o[1]) << 16);
    pk.y = (unsigned)f2bf(o[2]) | ((unsigned)f2bf(o[3]) << 16);
    pk.z = (unsigned)f2bf(o[4]) | ((unsigned)f2bf(o[5]) << 16);
    pk.w = (unsigned)f2bf(o[6]) | ((unsigned)f2bf(o[7]) << 16);
    t[(size_t)row * 12 + q] = pk;
}

// ---------------- MFMA matmul: y = t @ W + b (rows are perm slots) ----------------

template<int STATS, int OBF>
__global__ void k_mm(const unsigned short* __restrict__ ta,
                     const unsigned short* __restrict__ Wt,
                     const float* __restrict__ bias, const int* __restrict__ perm,
                     unsigned short* __restrict__ yb, float* __restrict__ yf,
                     float* __restrict__ accg, int n)
{
    __shared__ float sred[2 * FD];
    const int tid  = threadIdx.x;
    const int lane = tid & 63;
    const int wv   = tid >> 6;
    const int colb = lane & 15;
    const int hg   = lane >> 4;
    const int rbase = blockIdx.x * 64 + wv * 16;
    const int r = rbase + colb;

    s16x8 a[3];
    if (r < n) {
        #pragma unroll
        for (int s = 0; s < 3; s++)
            a[s] = *reinterpret_cast<const s16x8*>(ta + (size_t)r * FD + s * 32 + hg * 8);
    } else {
        #pragma unroll
        for (int s = 0; s < 3; s++) a[s] = s16x8{0, 0, 0, 0, 0, 0, 0, 0};
    }
    s16x8 b[6][3];
    #pragma unroll
    for (int c2 = 0; c2 < 6; c2++)
        #pragma unroll
        for (int s = 0; s < 3; s++)
            b[c2][s] = *reinterpret_cast<const s16x8*>(Wt + (size_t)(c2 * 16 + colb) * FD + s * 32 + hg * 8);

    f32x4 acc[6];
    #pragma unroll
    for (int c2 = 0; c2 < 6; c2++) acc[c2] = (f32x4){0.f, 0.f, 0.f, 0.f};
    #pragma unroll
    for (int s = 0; s < 3; s++)
        #pragma unroll
        for (int c2 = 0; c2 < 6; c2++)
            acc[c2] = __builtin_amdgcn_mfma_f32_16x16x32_bf16(a[s], b[c2][s], acc[c2], 0, 0, 0);

    int orow[4];
    #pragma unroll
    for (int j = 0; j < 4; j++) {
        int rr = rbase + hg * 4 + j;
        orow[j] = (!OBF && rr < n) ? perm[rr] : rr;
    }
    float s1[6], s2[6];
    #pragma unroll
    for (int c2 = 0; c2 < 6; c2++) { s1[c2] = 0.f; s2[c2] = 0.f; }
    #pragma unroll
    for (int c2 = 0; c2 < 6; c2++) {
        float bc = bias[c2 * 16 + colb];
        #pragma unroll
        for (int j = 0; j < 4; j++) {
            int rr = rbase + hg * 4 + j;
            if (rr < n) {
                float y = acc[c2][j] + bc;
                if (OBF) yb[(size_t)rr * FD + c2 * 16 + colb] = f2bf(y);
                else     yf[(size_t)orow[j] * FD + c2 * 16 + colb] = y;
                if (STATS) { s1[c2] += y; s2[c2] = fmaf(y, y, s2[c2]); }
            }
        }
    }
    if (STATS) {
        if (tid < 2 * FD) sred[tid] = 0.f;
        __syncthreads();
        #pragma unroll
        for (int c2 = 0; c2 < 6; c2++) {
            float v1 = s1[c2], v2 = s2[c2];
            v1 += __shfl_xor(v1, 16, 64); v1 += __shfl_xor(v1, 32, 64);
            v2 += __shfl_xor(v2, 16, 64); v2 += __shfl_xor(v2, 32, 64);
            if (lane < 16) {
                atomicAdd(&sred[c2 * 16 + colb], v1);
                atomicAdd(&sred[FD + c2 * 16 + colb], v2);
            }
        }
        __syncthreads();
        if (tid < 2 * FD) atomicAdd(&accg[tid], sred[tid]);
    }
}

extern "C" void kernel_launch(void* const* d_in, const int* in_sizes, int n_in,
                              void* d_out, int out_size, void* d_ws, size_t ws_size,
                              hipStream_t stream) {
    const float* feat = (const float*)d_in[0];
    const float* W1   = (const float*)d_in[1];
    const float* b1   = (const float*)d_in[2];
    const float* g1   = (const float*)d_in[3];
    const float* be1  = (const float*)d_in[4];
    const float* W2   = (const float*)d_in[5];
    const float* b2   = (const float*)d_in[6];
    const float* g2   = (const float*)d_in[7];
    const float* be2  = (const float*)d_in[8];
    const float* W3   = (const float*)d_in[9];
    const float* b3   = (const float*)d_in[10];
    const int*   src  = (const int*)d_in[11];
    const int*   dst  = (const int*)d_in[12];

    const int n = in_sizes[0] / FD;   // 50000
    const int e = in_sizes[11];       // 800000
    const int nbkt = (n + BNODES - 1) >> BSH;     // 391
    const int chunk = (e + NBLK - 1) / NBLK;      // 3125

    char* w = (char*)d_ws;
    unsigned short* hA  = (unsigned short*)w; w += (size_t)n * FD * 2;   // perm-order h
    unsigned short* tb  = (unsigned short*)w; w += (size_t)n * FD * 2;   // t buffer (ebuf alias)
    unsigned short* Wt  = (unsigned short*)w; w += (size_t)3 * FD * FD * 2;
    int*   csr     = (int*)w;   w += (size_t)e * 4;
    int*   bcnt    = (int*)w;   w += 512 * 4;
    float* acc1    = (float*)w; w += 2 * FD * 4;   // zeroed by k_cscan (with acc2)
    float* acc2    = (float*)w; w += 2 * FD * 4;
    int*   bbase   = (int*)w;   w += 513 * 4;
    int*   hist2d  = (int*)w;   w += (size_t)512 * NBLK * 4;
    int*   cursor2d= (int*)w;   w += (size_t)512 * NBLK * 4;
    int*   rp2     = (int*)w;   w += (size_t)n * 4;
    int*   re2     = (int*)w;   w += (size_t)n * 4;
    float* invd2   = (float*)w; w += (size_t)n * 4;
    int*   perm    = (int*)w;   w += (size_t)n * 4;
    int*   invp    = (int*)w;   w += (size_t)n * 4;

    uint2* ebuf = (uint2*)tb;                      // dead after k_bsort
    unsigned short* hB = (unsigned short*)d_out;   // bf16 ping-pong inside d_out
    float* O = (float*)d_out;
    const float invN = 1.0f / (float)n;
    const int AGG_GRID = (n * 12 + 255) / 256;     // 2344
    const int MM_GRID  = (n + 63) / 64;            // 782
    const int n12 = n * 12;
    const int prep_items = e + n12 + 3 * FD * FD;

    k_h2d<<<NBLK, 256, 0, stream>>>(dst, hist2d, e, nbkt, chunk);
    k_cscan<<<nbkt, NBLK, 0, stream>>>(hist2d, cursor2d, bcnt, acc1);
    k_bscan<<<1, 512, 0, stream>>>(bcnt, bbase, nbkt);
    k_scat<<<NBLK, 256, 0, stream>>>(src, dst, cursor2d, bbase, ebuf, e, nbkt, chunk);
    k_bsort<<<nbkt, 256, 0, stream>>>(ebuf, bbase, csr, rp2, re2, invd2, perm, invp, n);
    k_prep<<<(prep_items + 255) / 256, 256, 0, stream>>>(csr, invp, e, feat, perm,
                                                         (uint4*)hA, n, W1, W2, W3, Wt);

    // layer 1: agg hA->tb, mm tb->hB (bf16 in d_out), stats->acc1
    k_agg<0><<<AGG_GRID, 256, 0, stream>>>((const uint4*)hA, rp2, re2, invd2, csr,
                                           nullptr, nullptr, nullptr, invN, (uint4*)tb, n);
    k_mm<1, 1><<<MM_GRID, 256, 0, stream>>>(tb, Wt, b1, perm, hB, nullptr, acc1, n);

    // layer 2: agg hB->tb (BN from acc1), mm tb->hA, stats->acc2
    k_agg<1><<<AGG_GRID, 256, 0, stream>>>((const uint4*)hB, rp2, re2, invd2, csr,
                                           acc1, g1, be1, invN, (uint4*)tb, n);
    k_mm<1, 1><<<MM_GRID, 256, 0, stream>>>(tb, Wt + FD * FD, b2, perm, hA, nullptr, acc2, n);

    // layer 3: agg hA->tb (BN from acc2), mm tb->d_out fp32 (original order via perm)
    k_agg<1><<<AGG_GRID, 256, 0, stream>>>((const uint4*)hA, rp2, re2, invd2, csr,
                                           acc2, g2, be2, invN, (uint4*)tb, n);
    k_mm<0, 0><<<MM_GRID, 256, 0, stream>>>(tb, Wt + 2 * FD * FD, b3, perm, nullptr, O, nullptr, n);
}